// Round 6
// baseline (248.757 us; speedup 1.0000x reference)
//
#include <hip/hip_runtime.h>

// B=2, C=4, D=64, H=256, W=256. 7-point |Laplacian| MSE between softmax probs
// (classes 1..3) and one-hot targets, mean over all 3*B*D*H*W terms.
//
// Plane-march in d, accumulator form. Tile = 32(w) x 30(h) interior; block =
// 256 threads = 8 quad-cols x 32 rows (rows 0/31 = h-halo, staged by their
// owner threads). w-halo = 2 cols x 30 rows = 60 scalars owned by threads
// 0..59 (loads GUARDED — R5 loaded them on all 256 threads and wasted VMEM
// slots). IDD=4 planes/block -> grid = 8(w) x 9(h) x 16(d) x 2(b) = 2304
// blocks = 9/CU; LDS 17.9 KB admits 8 resident blocks/CU = 32 waves/CU.
// R5's grid (1152 = 4.5/CU, 32% occupancy) was the latency-bound cap.
//
// In-loop barriers are raw `s_waitcnt lgkmcnt(0); s_barrier` (LDS ordering
// only) so the next-plane global prefetch stays in flight across them
// (__syncthreads drains vmcnt(0) - R3's stall). R4 lesson: no __launch_bounds__
// min-waves clause, no struct-valued conditional prefetch (scratch spills).

#define CS   (1 << 22)           // per-batch spatial size (d,h,w)
#define NTOT_INV (1.0f / 25165824.0f)
#define BIAS3 ((8 << 20) | (8 << 10) | 8)   // +8 bias per 10-bit one-hot field
#define BAR() asm volatile("s_waitcnt lgkmcnt(0)\n\ts_barrier" ::: "memory")

__device__ __forceinline__ void smax1(float x0, float x1, float x2, float x3,
                                      float vm, float& p1, float& p2, float& p3) {
    float m  = fmaxf(fmaxf(x0, x1), fmaxf(x2, x3));
    float e0 = __expf(x0 - m);
    float e1 = __expf(x1 - m);
    float e2 = __expf(x2 - m);
    float e3 = __expf(x3 - m);
    float r  = vm * __builtin_amdgcn_rcpf(e0 + e1 + e2 + e3);
    p1 = e1 * r; p2 = e2 * r; p3 = e3 * r;
}

// class k in {1,2,3} -> 1 << ((k-1)*10); class 0 / masked -> 0
__device__ __forceinline__ int ohenc(int t, int msk) {
    int nz = (t > 0) ? 1 : 0;
    return (nz << (((t - 1) & 3) * 10)) & msk;
}

__global__ __launch_bounds__(256) void boundary_loss_kernel(
        const float* __restrict__ L,
        const int*   __restrict__ T,
        float*       __restrict__ out) {
    const int tid = threadIdx.x;
    const int tw  = tid & 7;          // quad column 0..7 (4 w-voxels each)
    const int th  = tid >> 3;         // row 0..31 (rows 0,31 = h-halo)
    int bi = blockIdx.x;
    const int wt = bi & 7;  bi >>= 3;
    const int dt = bi & 15; bi >>= 4;
    const int ht = bi % 9;
    const int b  = bi / 9;

    const int   h0 = ht * 30;
    const int   h  = h0 + th - 1;
    const bool  hv = ((unsigned)h < 256u);
    const float vm = hv ? 1.f : 0.f;
    const int   ohm = hv ? ~0 : 0;
    const int   w0 = wt << 5;
    const int   sp = ((hv ? h : 0) << 8) | (w0 + (tw << 2));
    const int   tBase = b * CS + sp;
    const int   lBase = (b << 2) * CS + sp;
    const bool  live  = (th >= 1) && (th <= 30) && hv;
    const int   d0 = dt << 2;

    // w-halo column duty: threads 0..29 = left col, 30..59 = right col
    const bool  hd   = (tid < 60);
    const int   side = (tid >= 30) ? 1 : 0;
    const int   hr   = side ? (tid - 29) : (tid + 1);    // interior row 1..30
    const int   hh   = h0 + hr - 1;
    const int   hwv  = side ? (w0 + 32) : (w0 - 1);
    const bool  hvv  = hd && ((unsigned)hh < 256u) && ((unsigned)hwv < 256u);
    const float hvm  = hvv ? 1.f : 0.f;
    const int   hohm = hvv ? ~0 : 0;
    const int   hsp  = ((hvv ? hh : 0) << 8) | (hvv ? hwv : 0);
    const int   htB  = b * CS + hsp;
    const int   hlB  = (b << 2) * CS + hsp;

    __shared__ float P1[32][32], P2[32][32], P3[32][32];
    __shared__ int   OHS[32][32];
    __shared__ float HL1[2][32], HL2[2][32], HL3[2][32];
    __shared__ int   HLO[2][32];

    // loop-invariant w-neighbor pointers (halo col for edge quads)
    const int c0 = tw << 2;
    const float* lp1 = (tw == 0) ? &HL1[0][th] : &P1[th][c0 - 1];
    const float* lp2 = (tw == 0) ? &HL2[0][th] : &P2[th][c0 - 1];
    const float* lp3 = (tw == 0) ? &HL3[0][th] : &P3[th][c0 - 1];
    const int*   lpo = (tw == 0) ? &HLO[0][th] : &OHS[th][c0 - 1];
    const float* rp1 = (tw == 7) ? &HL1[1][th] : &P1[th][c0 + 4];
    const float* rp2 = (tw == 7) ? &HL2[1][th] : &P2[th][c0 + 4];
    const float* rp3 = (tw == 7) ? &HL3[1][th] : &P3[th][c0 + 4];
    const int*   rpo = (tw == 7) ? &HLO[1][th] : &OHS[th][c0 + 4];

    float4 c1, c2, c3; int4 coh;      // current plane probs / packed one-hot
    float4 a1, a2, a3; int4 aoh;      // running Laplacian accumulator
    float hc1 = 0.f, hc2 = 0.f, hc3 = 0.f; int hco = 0;   // halo col, cur plane
    float accv = 0.f;

    // ---- seed accumulator with plane d0-1 (zero outside volume) ----
    {
        const int  off = (dt > 0 ? d0 - 1 : 0) << 16;
        const float svm  = (dt > 0) ? vm : 0.f;
        const int   sohm = (dt > 0) ? ohm : 0;
        float4 q0 = *(const float4*)(L + lBase + off);
        float4 q1 = *(const float4*)(L + lBase + off + CS);
        float4 q2 = *(const float4*)(L + lBase + off + 2 * CS);
        float4 q3 = *(const float4*)(L + lBase + off + 3 * CS);
        int4   qt = *(const int4*)(T + tBase + off);
        smax1(q0.x, q1.x, q2.x, q3.x, svm, a1.x, a2.x, a3.x);
        smax1(q0.y, q1.y, q2.y, q3.y, svm, a1.y, a2.y, a3.y);
        smax1(q0.z, q1.z, q2.z, q3.z, svm, a1.z, a2.z, a3.z);
        smax1(q0.w, q1.w, q2.w, q3.w, svm, a1.w, a2.w, a3.w);
        aoh.x = ohenc(qt.x, sohm) + BIAS3; aoh.y = ohenc(qt.y, sohm) + BIAS3;
        aoh.z = ohenc(qt.z, sohm) + BIAS3; aoh.w = ohenc(qt.w, sohm) + BIAS3;
    }

    // ---- plane d0 -> cur (+ halo col) ----
    {
        const int off = d0 << 16;
        float4 q0 = *(const float4*)(L + lBase + off);
        float4 q1 = *(const float4*)(L + lBase + off + CS);
        float4 q2 = *(const float4*)(L + lBase + off + 2 * CS);
        float4 q3 = *(const float4*)(L + lBase + off + 3 * CS);
        int4   qt = *(const int4*)(T + tBase + off);
        float hx0 = 0.f, hx1 = 0.f, hx2 = 0.f, hx3 = 0.f; int hqt = 0;
        if (hd) {
            hx0 = L[hlB + off]; hx1 = L[hlB + off + CS];
            hx2 = L[hlB + off + 2 * CS]; hx3 = L[hlB + off + 3 * CS];
            hqt = T[htB + off];
        }
        smax1(q0.x, q1.x, q2.x, q3.x, vm, c1.x, c2.x, c3.x);
        smax1(q0.y, q1.y, q2.y, q3.y, vm, c1.y, c2.y, c3.y);
        smax1(q0.z, q1.z, q2.z, q3.z, vm, c1.z, c2.z, c3.z);
        smax1(q0.w, q1.w, q2.w, q3.w, vm, c1.w, c2.w, c3.w);
        coh.x = ohenc(qt.x, ohm); coh.y = ohenc(qt.y, ohm);
        coh.z = ohenc(qt.z, ohm); coh.w = ohenc(qt.w, ohm);
        smax1(hx0, hx1, hx2, hx3, hvm, hc1, hc2, hc3);
        hco = ohenc(hqt, hohm);
    }

    for (int i = 0; i < 4; ++i) {
        const int   dn   = d0 + i + 1;
        const float vmn  = (dn < 64) ? vm : 0.f;     // d-validity folded in
        const int   ohmn = (dn < 64) ? ohm : 0;
        const float hvmn = (dn < 64) ? hvm : 0.f;
        const int   hohmn = (dn < 64) ? hohm : 0;
        const int   off  = (dn < 64 ? dn : 63) << 16;

        // unconditional main-quad prefetch — stays in flight across both BARs
        float4 q0 = *(const float4*)(L + lBase + off);
        float4 q1 = *(const float4*)(L + lBase + off + CS);
        float4 q2 = *(const float4*)(L + lBase + off + 2 * CS);
        float4 q3 = *(const float4*)(L + lBase + off + 3 * CS);
        int4   qt = *(const int4*)(T + tBase + off);
        float hx0 = 0.f, hx1 = 0.f, hx2 = 0.f, hx3 = 0.f; int hqt = 0;
        if (hd) {                                   // 60/256 threads only
            hx0 = L[hlB + off]; hx1 = L[hlB + off + CS];
            hx2 = L[hlB + off + 2 * CS]; hx3 = L[hlB + off + 3 * CS];
            hqt = T[htB + off];
        }

        BAR();   // prior step's stencil readers done (lgkm only, vmcnt live)
        *(float4*)&P1[th][c0] = c1;
        *(float4*)&P2[th][c0] = c2;
        *(float4*)&P3[th][c0] = c3;
        *(int4*)&OHS[th][c0]  = coh;
        if (hd) {
            HL1[side][hr] = hc1; HL2[side][hr] = hc2; HL3[side][hr] = hc3;
            HLO[side][hr] = hco;
        }
        BAR();   // plane visible to all waves

        if (live) {
            float4 u, dn4; float lf, rt;
            u = *(float4*)&P1[th - 1][c0]; dn4 = *(float4*)&P1[th + 1][c0];
            lf = *lp1; rt = *rp1;
            a1.x += u.x + dn4.x + lf   + c1.y - 6.f * c1.x;
            a1.y += u.y + dn4.y + c1.x + c1.z - 6.f * c1.y;
            a1.z += u.z + dn4.z + c1.y + c1.w - 6.f * c1.z;
            a1.w += u.w + dn4.w + c1.z + rt   - 6.f * c1.w;
            u = *(float4*)&P2[th - 1][c0]; dn4 = *(float4*)&P2[th + 1][c0];
            lf = *lp2; rt = *rp2;
            a2.x += u.x + dn4.x + lf   + c2.y - 6.f * c2.x;
            a2.y += u.y + dn4.y + c2.x + c2.z - 6.f * c2.y;
            a2.z += u.z + dn4.z + c2.y + c2.w - 6.f * c2.z;
            a2.w += u.w + dn4.w + c2.z + rt   - 6.f * c2.w;
            u = *(float4*)&P3[th - 1][c0]; dn4 = *(float4*)&P3[th + 1][c0];
            lf = *lp3; rt = *rp3;
            a3.x += u.x + dn4.x + lf   + c3.y - 6.f * c3.x;
            a3.y += u.y + dn4.y + c3.x + c3.z - 6.f * c3.y;
            a3.z += u.z + dn4.z + c3.y + c3.w - 6.f * c3.z;
            a3.w += u.w + dn4.w + c3.z + rt   - 6.f * c3.w;

            int4 iu = *(int4*)&OHS[th - 1][c0];
            int4 id = *(int4*)&OHS[th + 1][c0];
            int  il = *lpo, ir = *rpo;
            aoh.x += iu.x + id.x + il    + coh.y - 6 * coh.x;
            aoh.y += iu.y + id.y + coh.x + coh.z - 6 * coh.y;
            aoh.z += iu.z + id.z + coh.y + coh.w - 6 * coh.z;
            aoh.w += iu.w + id.w + coh.z + ir    - 6 * coh.w;
        }

        // softmax of prefetched next plane (first use of the in-flight loads)
        float4 n1, n2, n3; int4 noh;
        smax1(q0.x, q1.x, q2.x, q3.x, vmn, n1.x, n2.x, n3.x);
        smax1(q0.y, q1.y, q2.y, q3.y, vmn, n1.y, n2.y, n3.y);
        smax1(q0.z, q1.z, q2.z, q3.z, vmn, n1.z, n2.z, n3.z);
        smax1(q0.w, q1.w, q2.w, q3.w, vmn, n1.w, n2.w, n3.w);
        noh.x = ohenc(qt.x, ohmn); noh.y = ohenc(qt.y, ohmn);
        noh.z = ohenc(qt.z, ohmn); noh.w = ohenc(qt.w, ohmn);
        float hn1, hn2, hn3;
        smax1(hx0, hx1, hx2, hx3, hvmn, hn1, hn2, hn3);
        int hno = ohenc(hqt, hohmn);

        if (live) {
            int t0 = aoh.x + noh.x, t1 = aoh.y + noh.y;
            int t2 = aoh.z + noh.z, t3 = aoh.w + noh.w;
            float lp, lt, df;
            lp = fabsf(a1.x + n1.x); lt = fabsf((float)((t0 & 1023) - 8));          df = lp - lt; accv = fmaf(df, df, accv);
            lp = fabsf(a2.x + n2.x); lt = fabsf((float)(((t0 >> 10) & 1023) - 8));  df = lp - lt; accv = fmaf(df, df, accv);
            lp = fabsf(a3.x + n3.x); lt = fabsf((float)(((t0 >> 20) & 1023) - 8));  df = lp - lt; accv = fmaf(df, df, accv);
            lp = fabsf(a1.y + n1.y); lt = fabsf((float)((t1 & 1023) - 8));          df = lp - lt; accv = fmaf(df, df, accv);
            lp = fabsf(a2.y + n2.y); lt = fabsf((float)(((t1 >> 10) & 1023) - 8));  df = lp - lt; accv = fmaf(df, df, accv);
            lp = fabsf(a3.y + n3.y); lt = fabsf((float)(((t1 >> 20) & 1023) - 8));  df = lp - lt; accv = fmaf(df, df, accv);
            lp = fabsf(a1.z + n1.z); lt = fabsf((float)((t2 & 1023) - 8));          df = lp - lt; accv = fmaf(df, df, accv);
            lp = fabsf(a2.z + n2.z); lt = fabsf((float)(((t2 >> 10) & 1023) - 8));  df = lp - lt; accv = fmaf(df, df, accv);
            lp = fabsf(a3.z + n3.z); lt = fabsf((float)(((t2 >> 20) & 1023) - 8));  df = lp - lt; accv = fmaf(df, df, accv);
            lp = fabsf(a1.w + n1.w); lt = fabsf((float)((t3 & 1023) - 8));          df = lp - lt; accv = fmaf(df, df, accv);
            lp = fabsf(a2.w + n2.w); lt = fabsf((float)(((t3 >> 10) & 1023) - 8));  df = lp - lt; accv = fmaf(df, df, accv);
            lp = fabsf(a3.w + n3.w); lt = fabsf((float)(((t3 >> 20) & 1023) - 8));  df = lp - lt; accv = fmaf(df, df, accv);
        }

        // rotate planes: cur seeds the next accumulator's "+1 from below"
        a1 = c1; a2 = c2; a3 = c3;
        aoh.x = coh.x + BIAS3; aoh.y = coh.y + BIAS3;
        aoh.z = coh.z + BIAS3; aoh.w = coh.w + BIAS3;
        c1 = n1; c2 = n2; c3 = n3; coh = noh;
        hc1 = hn1; hc2 = hn2; hc3 = hn3; hco = hno;
    }

    // block reduction: wave shuffle -> LDS -> one atomic
    for (int o = 32; o > 0; o >>= 1) accv += __shfl_down(accv, o, 64);
    __shared__ float wsum[4];
    if ((tid & 63) == 0) wsum[tid >> 6] = accv;
    __syncthreads();
    if (tid == 0)
        atomicAdd(out, (wsum[0] + wsum[1] + wsum[2] + wsum[3]) * NTOT_INV);
}

extern "C" void kernel_launch(void* const* d_in, const int* in_sizes, int n_in,
                              void* d_out, int out_size, void* d_ws, size_t ws_size,
                              hipStream_t stream) {
    const float* logits  = (const float*)d_in[0];
    const int*   targets = (const int*)d_in[1];
    float*       out     = (float*)d_out;

    hipMemsetAsync(out, 0, sizeof(float), stream);   // d_out is poisoned 0xAA
    boundary_loss_kernel<<<2304, 256, 0, stream>>>(logits, targets, out);
}

// Round 7
// 235.601 us; speedup vs baseline: 1.0558x; 1.0558x over previous
//
#include <hip/hip_runtime.h>

// B=2, C=4, D=64, H=256, W=256. 7-point |Laplacian| MSE between softmax probs
// (classes 1..3) and one-hot targets, mean over all 3*B*D*H*W terms.
//
// Plane-march in d, accumulator form. Tile = 32(w) x 30(h) interior; block =
// 256 threads = 8 quad-cols x 32 rows (rows 0/31 = h-halo). w-halo = 60
// scalars owned by threads 0..59 (guarded loads). IDD=4 -> 2304 blocks.
//
// R7 changes vs R6:
//  * 2-deep raw prefetch, fully unrolled: plane d+2's loads are issued while
//    plane d+1 is softmaxed, so the compiler can wait with vmcnt(N>0) on the
//    older set only. R6's VGPR=64 budget forced an early vmcnt(0) drain that
//    serialized every step (occupancy-invariant ~25 us/step). Extra ~20 VGPRs
//    deliberately push past the 64-reg/8-wave cliff.
//  * XCD swizzle, dt-major: blockIdx = [colHi(5b) | dt(4b) | wt(3b)] so all
//    16 d-tiles of a (wt,ht,b) column run on one XCD back-to-back -> the
//    2-of-6 overlap planes between adjacent d-tiles hit that XCD's L2.
//  * barriers stay lgkm-only (s_waitcnt lgkmcnt(0); s_barrier) so vmem
//    prefetch stays in flight across them. No __launch_bounds__ cap (R4
//    spill lesson); halo loads guarded (R5 lesson).

#define CS   (1 << 22)           // per-batch spatial size (d,h,w)
#define NTOT_INV (1.0f / 25165824.0f)
#define BIAS3 ((8 << 20) | (8 << 10) | 8)   // +8 bias per 10-bit one-hot field
#define BAR() asm volatile("s_waitcnt lgkmcnt(0)\n\ts_barrier" ::: "memory")

// issue one plane's raw loads into named registers S*0..S*t (+ guarded halo)
#define ISSUE(S, off)                                                        \
    S##0 = *(const float4*)(L + lBase + (off));                              \
    S##1 = *(const float4*)(L + lBase + (off) + CS);                         \
    S##2 = *(const float4*)(L + lBase + (off) + 2 * CS);                     \
    S##3 = *(const float4*)(L + lBase + (off) + 3 * CS);                     \
    S##t = *(const int4*)(T + tBase + (off));                                \
    if (hd) {                                                                \
        S##h0 = L[hlB + (off)];          S##h1 = L[hlB + (off) + CS];        \
        S##h2 = L[hlB + (off) + 2 * CS]; S##h3 = L[hlB + (off) + 3 * CS];    \
        S##hq = T[htB + (off)];                                              \
    }

__device__ __forceinline__ void smax1(float x0, float x1, float x2, float x3,
                                      float vm, float& p1, float& p2, float& p3) {
    float m  = fmaxf(fmaxf(x0, x1), fmaxf(x2, x3));
    float e0 = __expf(x0 - m);
    float e1 = __expf(x1 - m);
    float e2 = __expf(x2 - m);
    float e3 = __expf(x3 - m);
    float r  = vm * __builtin_amdgcn_rcpf(e0 + e1 + e2 + e3);
    p1 = e1 * r; p2 = e2 * r; p3 = e3 * r;
}

// class k in {1,2,3} -> 1 << ((k-1)*10); class 0 / masked -> 0
__device__ __forceinline__ int ohenc(int t, int msk) {
    int nz = (t > 0) ? 1 : 0;
    return (nz << (((t - 1) & 3) * 10)) & msk;
}

__global__ __launch_bounds__(256) void boundary_loss_kernel(
        const float* __restrict__ L,
        const int*   __restrict__ T,
        float*       __restrict__ out) {
    const int tid = threadIdx.x;
    const int tw  = tid & 7;          // quad column 0..7 (4 w-voxels each)
    const int th  = tid >> 3;         // row 0..31 (rows 0,31 = h-halo)

    // swizzled decode: bi = [colHi | dt | wt]; wt picks the XCD (bi&7),
    // dt varies fastest within an XCD -> d-overlap planes L2-resident.
    const int bi    = blockIdx.x;
    const int wt    = bi & 7;
    const int dt    = (bi >> 3) & 15;
    const int colHi = bi >> 7;        // 0..17
    const int ht    = colHi % 9;
    const int b     = colHi / 9;

    const int   h0 = ht * 30;
    const int   h  = h0 + th - 1;
    const bool  hv = ((unsigned)h < 256u);
    const float vm = hv ? 1.f : 0.f;
    const int   ohm = hv ? ~0 : 0;
    const int   w0 = wt << 5;
    const int   sp = ((hv ? h : 0) << 8) | (w0 + (tw << 2));
    const int   tBase = b * CS + sp;
    const int   lBase = (b << 2) * CS + sp;
    const bool  live  = (th >= 1) && (th <= 30) && hv;
    const int   d0 = dt << 2;

    // w-halo column duty: threads 0..29 = left col, 30..59 = right col
    const bool  hd   = (tid < 60);
    const int   side = (tid >= 30) ? 1 : 0;
    const int   hr   = side ? (tid - 29) : (tid + 1);    // interior row 1..30
    const int   hh   = h0 + hr - 1;
    const int   hwv  = side ? (w0 + 32) : (w0 - 1);
    const bool  hvv  = hd && ((unsigned)hh < 256u) && ((unsigned)hwv < 256u);
    const float hvm  = hvv ? 1.f : 0.f;
    const int   hohm = hvv ? ~0 : 0;
    const int   hsp  = ((hvv ? hh : 0) << 8) | (hvv ? hwv : 0);
    const int   htB  = b * CS + hsp;
    const int   hlB  = (b << 2) * CS + hsp;

    __shared__ float P1[32][32], P2[32][32], P3[32][32];
    __shared__ int   OHS[32][32];
    __shared__ float HL1[2][32], HL2[2][32], HL3[2][32];
    __shared__ int   HLO[2][32];

    // loop-invariant w-neighbor pointers (halo col for edge quads)
    const int c0 = tw << 2;
    const float* lp1 = (tw == 0) ? &HL1[0][th] : &P1[th][c0 - 1];
    const float* lp2 = (tw == 0) ? &HL2[0][th] : &P2[th][c0 - 1];
    const float* lp3 = (tw == 0) ? &HL3[0][th] : &P3[th][c0 - 1];
    const int*   lpo = (tw == 0) ? &HLO[0][th] : &OHS[th][c0 - 1];
    const float* rp1 = (tw == 7) ? &HL1[1][th] : &P1[th][c0 + 4];
    const float* rp2 = (tw == 7) ? &HL2[1][th] : &P2[th][c0 + 4];
    const float* rp3 = (tw == 7) ? &HL3[1][th] : &P3[th][c0 + 4];
    const int*   rpo = (tw == 7) ? &HLO[1][th] : &OHS[th][c0 + 4];

    float4 c1, c2, c3; int4 coh;      // current plane probs / packed one-hot
    float4 a1, a2, a3; int4 aoh;      // running Laplacian accumulator
    float hc1 = 0.f, hc2 = 0.f, hc3 = 0.f; int hco = 0;   // halo col, cur plane
    float accv = 0.f;

    // ---- seed accumulator with plane d0-1 (zero outside volume) ----
    {
        const int  off = (dt > 0 ? d0 - 1 : 0) << 16;
        const float svm  = (dt > 0) ? vm : 0.f;
        const int   sohm = (dt > 0) ? ohm : 0;
        float4 q0 = *(const float4*)(L + lBase + off);
        float4 q1 = *(const float4*)(L + lBase + off + CS);
        float4 q2 = *(const float4*)(L + lBase + off + 2 * CS);
        float4 q3 = *(const float4*)(L + lBase + off + 3 * CS);
        int4   qt = *(const int4*)(T + tBase + off);
        smax1(q0.x, q1.x, q2.x, q3.x, svm, a1.x, a2.x, a3.x);
        smax1(q0.y, q1.y, q2.y, q3.y, svm, a1.y, a2.y, a3.y);
        smax1(q0.z, q1.z, q2.z, q3.z, svm, a1.z, a2.z, a3.z);
        smax1(q0.w, q1.w, q2.w, q3.w, svm, a1.w, a2.w, a3.w);
        aoh.x = ohenc(qt.x, sohm) + BIAS3; aoh.y = ohenc(qt.y, sohm) + BIAS3;
        aoh.z = ohenc(qt.z, sohm) + BIAS3; aoh.w = ohenc(qt.w, sohm) + BIAS3;
    }

    // ---- plane d0 -> cur (+ halo col) ----
    {
        const int off = d0 << 16;
        float4 q0 = *(const float4*)(L + lBase + off);
        float4 q1 = *(const float4*)(L + lBase + off + CS);
        float4 q2 = *(const float4*)(L + lBase + off + 2 * CS);
        float4 q3 = *(const float4*)(L + lBase + off + 3 * CS);
        int4   qt = *(const int4*)(T + tBase + off);
        float hx0 = 0.f, hx1 = 0.f, hx2 = 0.f, hx3 = 0.f; int hqt = 0;
        if (hd) {
            hx0 = L[hlB + off]; hx1 = L[hlB + off + CS];
            hx2 = L[hlB + off + 2 * CS]; hx3 = L[hlB + off + 3 * CS];
            hqt = T[htB + off];
        }
        smax1(q0.x, q1.x, q2.x, q3.x, vm, c1.x, c2.x, c3.x);
        smax1(q0.y, q1.y, q2.y, q3.y, vm, c1.y, c2.y, c3.y);
        smax1(q0.z, q1.z, q2.z, q3.z, vm, c1.z, c2.z, c3.z);
        smax1(q0.w, q1.w, q2.w, q3.w, vm, c1.w, c2.w, c3.w);
        coh.x = ohenc(qt.x, ohm); coh.y = ohenc(qt.y, ohm);
        coh.z = ohenc(qt.z, ohm); coh.w = ohenc(qt.w, ohm);
        smax1(hx0, hx1, hx2, hx3, hvm, hc1, hc2, hc3);
        hco = ohenc(hqt, hohm);
    }

    // ---- prime 1st-level prefetch: raw plane d0+1 ----
    float4 A0, A1, A2, A3; int4 At;
    float Ah0 = 0.f, Ah1 = 0.f, Ah2 = 0.f, Ah3 = 0.f; int Ahq = 0;
    {
        const int off = (d0 + 1 < 64 ? d0 + 1 : 63) << 16;
        ISSUE(A, off)
    }

#pragma unroll
    for (int i = 0; i < 4; ++i) {
        // ---- issue 2nd-level prefetch (plane d0+i+2), skipped on last it ----
        float4 B0, B1, B2, B3; int4 Bt;
        float Bh0 = 0.f, Bh1 = 0.f, Bh2 = 0.f, Bh3 = 0.f; int Bhq = 0;
        B0 = B1 = B2 = B3 = make_float4(0.f, 0.f, 0.f, 0.f);
        Bt = make_int4(0, 0, 0, 0);
        if (i < 3) {
            const int off = (d0 + i + 2 < 64 ? d0 + i + 2 : 63) << 16;
            ISSUE(B, off)
        }

        BAR();   // prior step's stencil readers done (lgkm only, vmcnt live)
        *(float4*)&P1[th][c0] = c1;
        *(float4*)&P2[th][c0] = c2;
        *(float4*)&P3[th][c0] = c3;
        *(int4*)&OHS[th][c0]  = coh;
        if (hd) {
            HL1[side][hr] = hc1; HL2[side][hr] = hc2; HL3[side][hr] = hc3;
            HLO[side][hr] = hco;
        }
        BAR();   // plane visible to all waves

        if (live) {
            float4 u, dn4; float lf, rt;
            u = *(float4*)&P1[th - 1][c0]; dn4 = *(float4*)&P1[th + 1][c0];
            lf = *lp1; rt = *rp1;
            a1.x += u.x + dn4.x + lf   + c1.y - 6.f * c1.x;
            a1.y += u.y + dn4.y + c1.x + c1.z - 6.f * c1.y;
            a1.z += u.z + dn4.z + c1.y + c1.w - 6.f * c1.z;
            a1.w += u.w + dn4.w + c1.z + rt   - 6.f * c1.w;
            u = *(float4*)&P2[th - 1][c0]; dn4 = *(float4*)&P2[th + 1][c0];
            lf = *lp2; rt = *rp2;
            a2.x += u.x + dn4.x + lf   + c2.y - 6.f * c2.x;
            a2.y += u.y + dn4.y + c2.x + c2.z - 6.f * c2.y;
            a2.z += u.z + dn4.z + c2.y + c2.w - 6.f * c2.z;
            a2.w += u.w + dn4.w + c2.z + rt   - 6.f * c2.w;
            u = *(float4*)&P3[th - 1][c0]; dn4 = *(float4*)&P3[th + 1][c0];
            lf = *lp3; rt = *rp3;
            a3.x += u.x + dn4.x + lf   + c3.y - 6.f * c3.x;
            a3.y += u.y + dn4.y + c3.x + c3.z - 6.f * c3.y;
            a3.z += u.z + dn4.z + c3.y + c3.w - 6.f * c3.z;
            a3.w += u.w + dn4.w + c3.z + rt   - 6.f * c3.w;

            int4 iu = *(int4*)&OHS[th - 1][c0];
            int4 id = *(int4*)&OHS[th + 1][c0];
            int  il = *lpo, ir = *rpo;
            aoh.x += iu.x + id.x + il    + coh.y - 6 * coh.x;
            aoh.y += iu.y + id.y + coh.x + coh.z - 6 * coh.y;
            aoh.z += iu.z + id.z + coh.y + coh.w - 6 * coh.z;
            aoh.w += iu.w + id.w + coh.z + ir    - 6 * coh.w;
        }

        // ---- cook the OLDER prefetch set (plane d0+i+1) ----
        // compiler waits vmcnt(N) for A only; B's loads stay outstanding
        const int   dnA   = d0 + i + 1;
        const float vmn   = (dnA < 64) ? vm : 0.f;
        const int   ohmn  = (dnA < 64) ? ohm : 0;
        const float hvmn  = (dnA < 64) ? hvm : 0.f;
        const int   hohmn = (dnA < 64) ? hohm : 0;
        float4 n1, n2, n3; int4 noh;
        smax1(A0.x, A1.x, A2.x, A3.x, vmn, n1.x, n2.x, n3.x);
        smax1(A0.y, A1.y, A2.y, A3.y, vmn, n1.y, n2.y, n3.y);
        smax1(A0.z, A1.z, A2.z, A3.z, vmn, n1.z, n2.z, n3.z);
        smax1(A0.w, A1.w, A2.w, A3.w, vmn, n1.w, n2.w, n3.w);
        noh.x = ohenc(At.x, ohmn); noh.y = ohenc(At.y, ohmn);
        noh.z = ohenc(At.z, ohmn); noh.w = ohenc(At.w, ohmn);
        float hn1, hn2, hn3;
        smax1(Ah0, Ah1, Ah2, Ah3, hvmn, hn1, hn2, hn3);
        int hno = ohenc(Ahq, hohmn);

        if (live) {
            int t0 = aoh.x + noh.x, t1 = aoh.y + noh.y;
            int t2 = aoh.z + noh.z, t3 = aoh.w + noh.w;
            float lp, lt, df;
            lp = fabsf(a1.x + n1.x); lt = fabsf((float)((t0 & 1023) - 8));          df = lp - lt; accv = fmaf(df, df, accv);
            lp = fabsf(a2.x + n2.x); lt = fabsf((float)(((t0 >> 10) & 1023) - 8));  df = lp - lt; accv = fmaf(df, df, accv);
            lp = fabsf(a3.x + n3.x); lt = fabsf((float)(((t0 >> 20) & 1023) - 8));  df = lp - lt; accv = fmaf(df, df, accv);
            lp = fabsf(a1.y + n1.y); lt = fabsf((float)((t1 & 1023) - 8));          df = lp - lt; accv = fmaf(df, df, accv);
            lp = fabsf(a2.y + n2.y); lt = fabsf((float)(((t1 >> 10) & 1023) - 8));  df = lp - lt; accv = fmaf(df, df, accv);
            lp = fabsf(a3.y + n3.y); lt = fabsf((float)(((t1 >> 20) & 1023) - 8));  df = lp - lt; accv = fmaf(df, df, accv);
            lp = fabsf(a1.z + n1.z); lt = fabsf((float)((t2 & 1023) - 8));          df = lp - lt; accv = fmaf(df, df, accv);
            lp = fabsf(a2.z + n2.z); lt = fabsf((float)(((t2 >> 10) & 1023) - 8));  df = lp - lt; accv = fmaf(df, df, accv);
            lp = fabsf(a3.z + n3.z); lt = fabsf((float)(((t2 >> 20) & 1023) - 8));  df = lp - lt; accv = fmaf(df, df, accv);
            lp = fabsf(a1.w + n1.w); lt = fabsf((float)((t3 & 1023) - 8));          df = lp - lt; accv = fmaf(df, df, accv);
            lp = fabsf(a2.w + n2.w); lt = fabsf((float)(((t3 >> 10) & 1023) - 8));  df = lp - lt; accv = fmaf(df, df, accv);
            lp = fabsf(a3.w + n3.w); lt = fabsf((float)(((t3 >> 20) & 1023) - 8));  df = lp - lt; accv = fmaf(df, df, accv);
        }

        // rotate: cur seeds next accumulator; cooked A becomes cur; B -> A
        a1 = c1; a2 = c2; a3 = c3;
        aoh.x = coh.x + BIAS3; aoh.y = coh.y + BIAS3;
        aoh.z = coh.z + BIAS3; aoh.w = coh.w + BIAS3;
        c1 = n1; c2 = n2; c3 = n3; coh = noh;
        hc1 = hn1; hc2 = hn2; hc3 = hn3; hco = hno;
        A0 = B0; A1 = B1; A2 = B2; A3 = B3; At = Bt;
        Ah0 = Bh0; Ah1 = Bh1; Ah2 = Bh2; Ah3 = Bh3; Ahq = Bhq;
    }

    // block reduction: wave shuffle -> LDS -> one atomic
    for (int o = 32; o > 0; o >>= 1) accv += __shfl_down(accv, o, 64);
    __shared__ float wsum[4];
    if ((tid & 63) == 0) wsum[tid >> 6] = accv;
    __syncthreads();
    if (tid == 0)
        atomicAdd(out, (wsum[0] + wsum[1] + wsum[2] + wsum[3]) * NTOT_INV);
}

extern "C" void kernel_launch(void* const* d_in, const int* in_sizes, int n_in,
                              void* d_out, int out_size, void* d_ws, size_t ws_size,
                              hipStream_t stream) {
    const float* logits  = (const float*)d_in[0];
    const int*   targets = (const int*)d_in[1];
    float*       out     = (float*)d_out;

    hipMemsetAsync(out, 0, sizeof(float), stream);   // d_out is poisoned 0xAA
    boundary_loss_kernel<<<2304, 256, 0, stream>>>(logits, targets, out);
}

// Round 8
// 217.069 us; speedup vs baseline: 1.1460x; 1.0854x over previous
//
#include <hip/hip_runtime.h>

// B=2, C=4, D=64, H=256, W=256. 7-point |Laplacian| MSE between softmax probs
// (classes 1..3) and one-hot targets, mean over all 3*B*D*H*W terms.
//
// R8: full-width-wave structure. One wave = one full w-row (lane i owns
// w=4i..4i+3, 64 lanes x 4 = 256): every global load is one CONTIGUOUS 1 KB
// burst per wave (the 6.3 TB/s ubench pattern). R5-R7 all pinned at
// dur == FETCH/3.0 TB/s with 8x128B scattered wave-loads + 300 wasted-line
// halo scalars/step; this kernel has ZERO halo loads - w-neighbors come from
// 8 __shfl's (w boundary zero-pad = lane 0/63 select), h-neighbors from LDS
// (8 rows/block), d-neighbors from the march accumulator (R7 algebra).
//
// Block = 512 thr = 8 waves = 8 h-rows (rows 0/7 = h-halo: load+cook+stage
// only, no retire). March d, IDD=8 (plane d0-1..d0+8 -> 1.25x d-redundancy,
// 1.33x h -> ~280 MB requested). Grid = 43(h) x 8(d) x 2(b) = 688 blocks.
// Barriers stay lgkm-only (prefetch lives across them); 2-deep prefetch;
// no __launch_bounds__ cap (R4 spill lesson).

#define CS   (1 << 22)           // per-batch spatial size (d,h,w)
#define NTOT_INV (1.0f / 25165824.0f)
#define BIAS3 ((8 << 20) | (8 << 10) | 8)   // +8 bias per 10-bit one-hot field
#define BAR() asm volatile("s_waitcnt lgkmcnt(0)\n\ts_barrier" ::: "memory")

// issue one plane's raw loads (4 logit channels + targets), contiguous 1 KB/wave
#define ISSUE(S, off)                                                        \
    S##0 = *(const float4*)(L + lBase + (off));                              \
    S##1 = *(const float4*)(L + lBase + (off) + CS);                         \
    S##2 = *(const float4*)(L + lBase + (off) + 2 * CS);                     \
    S##3 = *(const float4*)(L + lBase + (off) + 3 * CS);                     \
    S##t = *(const int4*)(T + tBase + (off));

__device__ __forceinline__ void smax1(float x0, float x1, float x2, float x3,
                                      float vm, float& p1, float& p2, float& p3) {
    float m  = fmaxf(fmaxf(x0, x1), fmaxf(x2, x3));
    float e0 = __expf(x0 - m);
    float e1 = __expf(x1 - m);
    float e2 = __expf(x2 - m);
    float e3 = __expf(x3 - m);
    float r  = vm * __builtin_amdgcn_rcpf(e0 + e1 + e2 + e3);
    p1 = e1 * r; p2 = e2 * r; p3 = e3 * r;
}

// class k in {1,2,3} -> 1 << ((k-1)*10); class 0 / masked -> 0
__device__ __forceinline__ int ohenc(int t, int msk) {
    int nz = (t > 0) ? 1 : 0;
    return (nz << (((t - 1) & 3) * 10)) & msk;
}

__global__ __launch_bounds__(512) void boundary_loss_kernel(
        const float* __restrict__ L,
        const int*   __restrict__ T,
        float*       __restrict__ out) {
    const int tid  = threadIdx.x;
    const int lane = tid & 63;        // quad column: w = lane*4 .. lane*4+3
    const int th   = tid >> 6;        // h-row in block 0..7 (0,7 = h-halo)
    int bi = blockIdx.x;
    const int dseg = bi & 7;  bi >>= 3;      // d fastest: adjacent d-segs share 2 planes
    const int ht   = bi % 43;
    const int b    = bi / 43;

    const int   h   = ht * 6 + th - 1;
    const bool  hv  = ((unsigned)h < 256u);
    const int   hcl = min(max(h, 0), 255);   // clamp OOB rows to a safe address
    const float vm  = hv ? 1.f : 0.f;
    const int   ohm = hv ? ~0 : 0;
    const bool  live = (th >= 1) && (th <= 6) && hv;   // wave-uniform
    const int   d0  = dseg << 3;

    const int rowoff = (hcl << 8) + (lane << 2);
    const int tBase  = b * CS + rowoff;
    const int lBase  = (b << 2) * CS + rowoff;

    __shared__ float P1[8][256], P2[8][256], P3[8][256];
    __shared__ int   OH[8][256];

    const int c0 = lane << 2;

    float4 c1, c2, c3; int4 coh;      // current plane probs / packed one-hot
    float4 a1, a2, a3; int4 aoh;      // running Laplacian accumulator
    float accv = 0.f;

    // ---- seed accumulator with plane d0-1 (zero outside volume) ----
    {
        const int   off  = (dseg > 0 ? d0 - 1 : 0) << 16;
        const float svm  = (dseg > 0) ? vm : 0.f;
        const int   sohm = (dseg > 0) ? ohm : 0;
        float4 q0, q1, q2, q3; int4 qt;
        ISSUE(q, off)
        smax1(q0.x, q1.x, q2.x, q3.x, svm, a1.x, a2.x, a3.x);
        smax1(q0.y, q1.y, q2.y, q3.y, svm, a1.y, a2.y, a3.y);
        smax1(q0.z, q1.z, q2.z, q3.z, svm, a1.z, a2.z, a3.z);
        smax1(q0.w, q1.w, q2.w, q3.w, svm, a1.w, a2.w, a3.w);
        aoh.x = ohenc(qt.x, sohm) + BIAS3; aoh.y = ohenc(qt.y, sohm) + BIAS3;
        aoh.z = ohenc(qt.z, sohm) + BIAS3; aoh.w = ohenc(qt.w, sohm) + BIAS3;
    }

    // ---- plane d0 -> cur ----
    {
        const int off = d0 << 16;
        float4 q0, q1, q2, q3; int4 qt;
        ISSUE(q, off)
        smax1(q0.x, q1.x, q2.x, q3.x, vm, c1.x, c2.x, c3.x);
        smax1(q0.y, q1.y, q2.y, q3.y, vm, c1.y, c2.y, c3.y);
        smax1(q0.z, q1.z, q2.z, q3.z, vm, c1.z, c2.z, c3.z);
        smax1(q0.w, q1.w, q2.w, q3.w, vm, c1.w, c2.w, c3.w);
        coh.x = ohenc(qt.x, ohm); coh.y = ohenc(qt.y, ohm);
        coh.z = ohenc(qt.z, ohm); coh.w = ohenc(qt.w, ohm);
    }

    // ---- prime 1st-level prefetch: raw plane d0+1 ----
    float4 A0, A1, A2, A3; int4 At;
    {
        const int off = (d0 + 1 < 64 ? d0 + 1 : 63) << 16;
        ISSUE(A, off)
    }

#pragma unroll
    for (int i = 0; i < 8; ++i) {
        // ---- issue 2nd-level prefetch (plane d0+i+2); static skip on last ----
        float4 B0, B1, B2, B3; int4 Bt;
        B0 = B1 = B2 = B3 = make_float4(0.f, 0.f, 0.f, 0.f);
        Bt = make_int4(0, 0, 0, 0);
        if (i < 7) {
            const int off = (d0 + i + 2 < 64 ? d0 + i + 2 : 63) << 16;
            ISSUE(B, off)
        }

        BAR();   // prior step's LDS readers done (lgkm only, vmcnt stays live)
        *(float4*)&P1[th][c0] = c1;
        *(float4*)&P2[th][c0] = c2;
        *(float4*)&P3[th][c0] = c3;
        *(int4*)&OH[th][c0]   = coh;
        BAR();   // plane visible to neighbor rows

        if (live) {   // wave-uniform branch; shuffles safe inside
            // w-neighbors across quads via shuffle; w=0/255 zero-pad
            float l1 = __shfl_up(c1.w, 1, 64);   float r1 = __shfl_down(c1.x, 1, 64);
            float l2 = __shfl_up(c2.w, 1, 64);   float r2 = __shfl_down(c2.x, 1, 64);
            float l3 = __shfl_up(c3.w, 1, 64);   float r3 = __shfl_down(c3.x, 1, 64);
            int   lo = __shfl_up(coh.w, 1, 64);  int   ro = __shfl_down(coh.x, 1, 64);
            if (lane == 0)  { l1 = l2 = l3 = 0.f; lo = 0; }
            if (lane == 63) { r1 = r2 = r3 = 0.f; ro = 0; }

            float4 u, v;
            u = *(float4*)&P1[th - 1][c0]; v = *(float4*)&P1[th + 1][c0];
            a1.x += u.x + v.x + l1   + c1.y - 6.f * c1.x;
            a1.y += u.y + v.y + c1.x + c1.z - 6.f * c1.y;
            a1.z += u.z + v.z + c1.y + c1.w - 6.f * c1.z;
            a1.w += u.w + v.w + c1.z + r1   - 6.f * c1.w;
            u = *(float4*)&P2[th - 1][c0]; v = *(float4*)&P2[th + 1][c0];
            a2.x += u.x + v.x + l2   + c2.y - 6.f * c2.x;
            a2.y += u.y + v.y + c2.x + c2.z - 6.f * c2.y;
            a2.z += u.z + v.z + c2.y + c2.w - 6.f * c2.z;
            a2.w += u.w + v.w + c2.z + r2   - 6.f * c2.w;
            u = *(float4*)&P3[th - 1][c0]; v = *(float4*)&P3[th + 1][c0];
            a3.x += u.x + v.x + l3   + c3.y - 6.f * c3.x;
            a3.y += u.y + v.y + c3.x + c3.z - 6.f * c3.y;
            a3.z += u.z + v.z + c3.y + c3.w - 6.f * c3.z;
            a3.w += u.w + v.w + c3.z + r3   - 6.f * c3.w;

            int4 iu = *(int4*)&OH[th - 1][c0];
            int4 id = *(int4*)&OH[th + 1][c0];
            aoh.x += iu.x + id.x + lo    + coh.y - 6 * coh.x;
            aoh.y += iu.y + id.y + coh.x + coh.z - 6 * coh.y;
            aoh.z += iu.z + id.z + coh.y + coh.w - 6 * coh.z;
            aoh.w += iu.w + id.w + coh.z + ro    - 6 * coh.w;
        }

        // ---- cook the OLDER prefetch set (plane d0+i+1) ----
        const int   dnA  = d0 + i + 1;
        const float vmn  = (dnA < 64) ? vm : 0.f;
        const int   ohmn = (dnA < 64) ? ohm : 0;
        float4 n1, n2, n3; int4 noh;
        smax1(A0.x, A1.x, A2.x, A3.x, vmn, n1.x, n2.x, n3.x);
        smax1(A0.y, A1.y, A2.y, A3.y, vmn, n1.y, n2.y, n3.y);
        smax1(A0.z, A1.z, A2.z, A3.z, vmn, n1.z, n2.z, n3.z);
        smax1(A0.w, A1.w, A2.w, A3.w, vmn, n1.w, n2.w, n3.w);
        noh.x = ohenc(At.x, ohmn); noh.y = ohenc(At.y, ohmn);
        noh.z = ohenc(At.z, ohmn); noh.w = ohenc(At.w, ohmn);

        if (live) {
            int t0 = aoh.x + noh.x, t1 = aoh.y + noh.y;
            int t2 = aoh.z + noh.z, t3 = aoh.w + noh.w;
            float lp, lt, df;
            lp = fabsf(a1.x + n1.x); lt = fabsf((float)((t0 & 1023) - 8));          df = lp - lt; accv = fmaf(df, df, accv);
            lp = fabsf(a2.x + n2.x); lt = fabsf((float)(((t0 >> 10) & 1023) - 8));  df = lp - lt; accv = fmaf(df, df, accv);
            lp = fabsf(a3.x + n3.x); lt = fabsf((float)(((t0 >> 20) & 1023) - 8));  df = lp - lt; accv = fmaf(df, df, accv);
            lp = fabsf(a1.y + n1.y); lt = fabsf((float)((t1 & 1023) - 8));          df = lp - lt; accv = fmaf(df, df, accv);
            lp = fabsf(a2.y + n2.y); lt = fabsf((float)(((t1 >> 10) & 1023) - 8));  df = lp - lt; accv = fmaf(df, df, accv);
            lp = fabsf(a3.y + n3.y); lt = fabsf((float)(((t1 >> 20) & 1023) - 8));  df = lp - lt; accv = fmaf(df, df, accv);
            lp = fabsf(a1.z + n1.z); lt = fabsf((float)((t2 & 1023) - 8));          df = lp - lt; accv = fmaf(df, df, accv);
            lp = fabsf(a2.z + n2.z); lt = fabsf((float)(((t2 >> 10) & 1023) - 8));  df = lp - lt; accv = fmaf(df, df, accv);
            lp = fabsf(a3.z + n3.z); lt = fabsf((float)(((t2 >> 20) & 1023) - 8));  df = lp - lt; accv = fmaf(df, df, accv);
            lp = fabsf(a1.w + n1.w); lt = fabsf((float)((t3 & 1023) - 8));          df = lp - lt; accv = fmaf(df, df, accv);
            lp = fabsf(a2.w + n2.w); lt = fabsf((float)(((t3 >> 10) & 1023) - 8));  df = lp - lt; accv = fmaf(df, df, accv);
            lp = fabsf(a3.w + n3.w); lt = fabsf((float)(((t3 >> 20) & 1023) - 8));  df = lp - lt; accv = fmaf(df, df, accv);
        }

        // rotate: cur seeds next accumulator; cooked A becomes cur; B -> A
        a1 = c1; a2 = c2; a3 = c3;
        aoh.x = coh.x + BIAS3; aoh.y = coh.y + BIAS3;
        aoh.z = coh.z + BIAS3; aoh.w = coh.w + BIAS3;
        c1 = n1; c2 = n2; c3 = n3; coh = noh;
        A0 = B0; A1 = B1; A2 = B2; A3 = B3; At = Bt;
    }

    // block reduction: wave shuffle -> LDS -> one atomic
    for (int o = 32; o > 0; o >>= 1) accv += __shfl_down(accv, o, 64);
    __shared__ float wsum[8];
    if (lane == 0) wsum[th] = accv;
    __syncthreads();
    if (tid == 0) {
        float s = wsum[0] + wsum[1] + wsum[2] + wsum[3]
                + wsum[4] + wsum[5] + wsum[6] + wsum[7];
        atomicAdd(out, s * NTOT_INV);
    }
}

extern "C" void kernel_launch(void* const* d_in, const int* in_sizes, int n_in,
                              void* d_out, int out_size, void* d_ws, size_t ws_size,
                              hipStream_t stream) {
    const float* logits  = (const float*)d_in[0];
    const int*   targets = (const int*)d_in[1];
    float*       out     = (float*)d_out;

    hipMemsetAsync(out, 0, sizeof(float), stream);   // d_out is poisoned 0xAA
    boundary_loss_kernel<<<688, 512, 0, stream>>>(logits, targets, out);
}